// Round 1
// baseline (907.354 us; speedup 1.0000x reference)
//
#include <hip/hip_runtime.h>
#include <math.h>

#define NN 131072      // nodes
#define NE 2097152     // edges
#define HD 32          // feature dim

__device__ __forceinline__ float softplus(float x) {
    return fmaxf(x, 0.f) + log1pf(expf(-fabsf(x)));
}

// ---------- CSR build ----------

__global__ void hist_kernel(const int* __restrict__ dst, int* __restrict__ cnt) {
    int e = blockIdx.x * blockDim.x + threadIdx.x;
    if (e < NE) atomicAdd(&cnt[dst[e]], 1);
}

__global__ void block_sum_kernel(const int* __restrict__ cnt, int* __restrict__ bsum) {
    __shared__ int sd[1024];
    int t = threadIdx.x;
    sd[t] = cnt[blockIdx.x * 1024 + t];
    __syncthreads();
    for (int off = 512; off > 0; off >>= 1) {
        if (t < off) sd[t] += sd[t + off];
        __syncthreads();
    }
    if (t == 0) bsum[blockIdx.x] = sd[0];
}

__global__ void scan_bsum_kernel(const int* __restrict__ bsum, int* __restrict__ boff,
                                 int* __restrict__ row_start) {
    if (threadIdx.x == 0 && blockIdx.x == 0) {
        int acc = 0;
        for (int i = 0; i < NN / 1024; ++i) { boff[i] = acc; acc += bsum[i]; }
        row_start[NN] = acc;   // == NE
    }
}

__global__ void scan_apply_kernel(const int* __restrict__ cnt, const int* __restrict__ boff,
                                  int* __restrict__ row_start, float* __restrict__ deg_inv) {
    __shared__ int sd[1024];
    int t = threadIdx.x;
    int i = blockIdx.x * 1024 + t;
    int c = cnt[i];
    sd[t] = c;
    __syncthreads();
    // Hillis-Steele inclusive scan
    for (int off = 1; off < 1024; off <<= 1) {
        int add = (t >= off) ? sd[t - off] : 0;
        __syncthreads();
        sd[t] += add;
        __syncthreads();
    }
    row_start[i] = boff[blockIdx.x] + sd[t] - c;     // exclusive
    deg_inv[i]   = (c > 0) ? (1.0f / (float)c) : 0.0f;
}

__global__ void scatter_kernel(const int* __restrict__ src, const int* __restrict__ dst,
                               const int* __restrict__ row_start, int* __restrict__ cursor,
                               int* __restrict__ sorted_src) {
    int e = blockIdx.x * blockDim.x + threadIdx.x;
    if (e < NE) {
        int d = dst[e];
        int p = atomicAdd(&cursor[d], 1);
        sorted_src[row_start[d] + p] = src[e];
    }
}

// ---------- fused GIN layer: hout = relu((hin + mean_agg(hin)) @ W + b) ----------
// one 32-lane group per node; 8 nodes per 256-thread block

__global__ __launch_bounds__(256) void layer_kernel(
        const float* __restrict__ hin, const float* __restrict__ W, const float* __restrict__ b,
        const int* __restrict__ row_start, const int* __restrict__ sorted_src,
        const float* __restrict__ deg_inv, float* __restrict__ hout) {
    __shared__ float Wl[1024];
    __shared__ float bl[32];
    int t = threadIdx.x;
    for (int i = t; i < 1024; i += 256) Wl[i] = W[i];
    if (t < 32) bl[t] = b[t];
    __syncthreads();

    int node = (blockIdx.x << 3) + (t >> 5);
    int lane = t & 31;
    int beg = row_start[node];
    int end = row_start[node + 1];
    float a = 0.f;
    for (int e = beg; e < end; ++e) {
        int s = sorted_src[e];
        a += hin[(s << 5) + lane];
    }
    float v = hin[(node << 5) + lane] + a * deg_inv[node];
    float acc = bl[lane];
    #pragma unroll
    for (int k = 0; k < 32; ++k) {
        acc = fmaf(__shfl(v, k, 32), Wl[(k << 5) + lane], acc);
    }
    hout[(node << 5) + lane] = fmaxf(acc, 0.f);
}

// ---------- fused final neg layer + scoring: loss += softplus(dot(relu(...), s)) ----------

__global__ __launch_bounds__(256) void layer_score_kernel(
        const float* __restrict__ hin, const float* __restrict__ W, const float* __restrict__ b,
        const int* __restrict__ row_start, const int* __restrict__ sorted_src,
        const float* __restrict__ deg_inv, const float* __restrict__ svec,
        float* __restrict__ loss) {
    __shared__ float Wl[1024];
    __shared__ float bl[32];
    __shared__ float sl[32];
    __shared__ float part[8];
    int t = threadIdx.x;
    for (int i = t; i < 1024; i += 256) Wl[i] = W[i];
    if (t < 32) { bl[t] = b[t]; sl[t] = svec[t]; }
    __syncthreads();

    int node = (blockIdx.x << 3) + (t >> 5);
    int lane = t & 31;
    int beg = row_start[node];
    int end = row_start[node + 1];
    float a = 0.f;
    for (int e = beg; e < end; ++e) {
        int s = sorted_src[e];
        a += hin[(s << 5) + lane];
    }
    float v = hin[(node << 5) + lane] + a * deg_inv[node];
    float acc = bl[lane];
    #pragma unroll
    for (int k = 0; k < 32; ++k) {
        acc = fmaf(__shfl(v, k, 32), Wl[(k << 5) + lane], acc);
    }
    acc = fmaxf(acc, 0.f);
    // dot with s across the 32-lane group
    float w = acc * sl[lane];
    #pragma unroll
    for (int off = 16; off > 0; off >>= 1) w += __shfl_xor(w, off, 32);
    if (lane == 0) part[t >> 5] = softplus(w);   // target=0 -> softplus(+x)
    __syncthreads();
    if (t == 0) {
        float sum = 0.f;
        #pragma unroll
        for (int i = 0; i < 8; ++i) sum += part[i];
        atomicAdd(loss, sum);
    }
}

// ---------- readout ----------

__global__ __launch_bounds__(256) void colsum_kernel(const float* __restrict__ h,
                                                     float* __restrict__ colsum) {
    __shared__ float sd[256];
    int t = threadIdx.x;
    int stride = gridDim.x * 256;   // multiple of 32 -> column stays fixed per thread
    float acc = 0.f;
    for (int i = blockIdx.x * 256 + t; i < NN * HD; i += stride) acc += h[i];
    sd[t] = acc;
    __syncthreads();
    for (int off = 128; off >= 32; off >>= 1) {
        if (t < off) sd[t] += sd[t + off];
        __syncthreads();
    }
    if (t < 32) atomicAdd(&colsum[t], sd[t]);
}

__global__ void finalize_s_kernel(const float* __restrict__ colsum, const float* __restrict__ Wd,
                                  float* __restrict__ svec) {
    __shared__ float sm[32];
    int t = threadIdx.x;
    if (t < 32) {
        float m = colsum[t] / (float)NN;
        sm[t] = 1.f / (1.f + expf(-m));
    }
    __syncthreads();
    if (t < 32) {
        float acc = 0.f;
        for (int j = 0; j < 32; ++j) acc += Wd[t * 32 + j] * sm[j];
        svec[t] = acc;
    }
}

__global__ __launch_bounds__(256) void score_pos_kernel(const float* __restrict__ h,
                                                        const float* __restrict__ svec,
                                                        float* __restrict__ loss) {
    __shared__ float sl[32];
    __shared__ float sd[256];
    int t = threadIdx.x;
    if (t < 32) sl[t] = svec[t];
    __syncthreads();
    float acc = 0.f;
    int stride = gridDim.x * 256;
    for (int n = blockIdx.x * 256 + t; n < NN; n += stride) {
        const float4* row = (const float4*)(h + (n << 5));
        float dot = 0.f;
        #pragma unroll
        for (int q = 0; q < 8; ++q) {
            float4 r = row[q];
            dot += r.x * sl[q * 4 + 0] + r.y * sl[q * 4 + 1]
                 + r.z * sl[q * 4 + 2] + r.w * sl[q * 4 + 3];
        }
        acc += softplus(-dot);   // target=1 -> softplus(-x)
    }
    sd[t] = acc;
    __syncthreads();
    for (int off = 128; off > 0; off >>= 1) {
        if (t < off) sd[t] += sd[t + off];
        __syncthreads();
    }
    if (t == 0) atomicAdd(loss, sd[0]);
}

__global__ void perm_gather_kernel(const float* __restrict__ feat, const int* __restrict__ perm,
                                   float* __restrict__ out) {
    int i = blockIdx.x * blockDim.x + threadIdx.x;   // over NN*HD
    int n = i >> 5, f = i & 31;
    out[i] = feat[(perm[n] << 5) + f];
}

__global__ void final_kernel(const float* __restrict__ loss, float* __restrict__ out) {
    if (threadIdx.x == 0 && blockIdx.x == 0)
        out[0] = (loss[0] + loss[1]) / (float)NN;
}

// ---------- launch ----------

extern "C" void kernel_launch(void* const* d_in, const int* in_sizes, int n_in,
                              void* d_out, int out_size, void* d_ws, size_t ws_size,
                              hipStream_t stream) {
    const float* feature = (const float*)d_in[0];
    const float* W1 = (const float*)d_in[1];
    const float* b1 = (const float*)d_in[2];
    const float* W2 = (const float*)d_in[3];
    const float* b2 = (const float*)d_in[4];
    const float* Wd = (const float*)d_in[5];
    const int* src  = (const int*)d_in[6];
    const int* dst  = (const int*)d_in[7];
    const int* perm = (const int*)d_in[8];
    // d_in[9] = cluster_idx: provably irrelevant (equal-size disjoint clusters -> global mean)
    float* out = (float*)d_out;

    char* ws = (char*)d_ws;
    size_t off = 0;
    auto alloc = [&](size_t bytes) -> char* {
        char* p = ws + off;
        off += (bytes + 255) & ~(size_t)255;
        return p;
    };
    int*   cursor     = (int*)  alloc((size_t)NN * 4);
    int*   row_start  = (int*)  alloc((size_t)(NN + 1) * 4);
    int*   bsum       = (int*)  alloc(128 * 4);
    int*   boff       = (int*)  alloc(128 * 4);
    int*   sorted_src = (int*)  alloc((size_t)NE * 4);
    float* deg_inv    = (float*)alloc((size_t)NN * 4);
    float* hA         = (float*)alloc((size_t)NN * HD * 4);
    float* hB         = (float*)alloc((size_t)NN * HD * 4);
    float* colsum     = (float*)alloc(32 * 4);
    float* svec       = (float*)alloc(32 * 4);
    float* loss       = (float*)alloc(2 * 4);

    hipMemsetAsync(cursor, 0, (size_t)NN * 4, stream);
    hipMemsetAsync(colsum, 0, 32 * 4, stream);
    hipMemsetAsync(loss, 0, 2 * 4, stream);

    // CSR build (group edges by dst)
    hist_kernel<<<NE / 256, 256, 0, stream>>>(dst, cursor);
    block_sum_kernel<<<NN / 1024, 1024, 0, stream>>>(cursor, bsum);
    scan_bsum_kernel<<<1, 64, 0, stream>>>(bsum, boff, row_start);
    scan_apply_kernel<<<NN / 1024, 1024, 0, stream>>>(cursor, boff, row_start, deg_inv);
    hipMemsetAsync(cursor, 0, (size_t)NN * 4, stream);
    scatter_kernel<<<NE / 256, 256, 0, stream>>>(src, dst, row_start, cursor, sorted_src);

    // positive pass
    layer_kernel<<<NN / 8, 256, 0, stream>>>(feature, W1, b1, row_start, sorted_src, deg_inv, hA);
    layer_kernel<<<NN / 8, 256, 0, stream>>>(hA, W2, b2, row_start, sorted_src, deg_inv, hB);

    // readout: s = Wd @ sigmoid(mean(pos))
    colsum_kernel<<<2048, 256, 0, stream>>>(hB, colsum);
    finalize_s_kernel<<<1, 64, 0, stream>>>(colsum, Wd, svec);

    // positive scores
    score_pos_kernel<<<2048, 256, 0, stream>>>(hB, svec, loss);

    // negative pass (corrupted features), second layer fused with scoring
    perm_gather_kernel<<<(NN * HD) / 256, 256, 0, stream>>>(feature, perm, hA);
    layer_kernel<<<NN / 8, 256, 0, stream>>>(hA, W1, b1, row_start, sorted_src, deg_inv, hB);
    layer_score_kernel<<<NN / 8, 256, 0, stream>>>(hB, W2, b2, row_start, sorted_src, deg_inv,
                                                   svec, loss + 1);

    final_kernel<<<1, 64, 0, stream>>>(loss, out);
}

// Round 2
// 716.317 us; speedup vs baseline: 1.2667x; 1.2667x over previous
//
#include <hip/hip_runtime.h>
#include <math.h>

#define NN 131072      // nodes
#define NE 2097152     // edges
#define HD 32          // feature dim

__device__ __forceinline__ float softplus(float x) {
    return fmaxf(x, 0.f) + log1pf(expf(-fabsf(x)));
}

// ---------- CSR build ----------

__global__ void hist_kernel(const int* __restrict__ dst, int* __restrict__ cnt) {
    int e = blockIdx.x * blockDim.x + threadIdx.x;
    if (e < NE) atomicAdd(&cnt[dst[e]], 1);
}

__global__ void block_sum_kernel(const int* __restrict__ cnt, int* __restrict__ bsum) {
    __shared__ int sd[1024];
    int t = threadIdx.x;
    sd[t] = cnt[blockIdx.x * 1024 + t];
    __syncthreads();
    for (int off = 512; off > 0; off >>= 1) {
        if (t < off) sd[t] += sd[t + off];
        __syncthreads();
    }
    if (t == 0) bsum[blockIdx.x] = sd[0];
}

__global__ void scan_bsum_kernel(const int* __restrict__ bsum, int* __restrict__ boff,
                                 int* __restrict__ row_start) {
    if (threadIdx.x == 0 && blockIdx.x == 0) {
        int acc = 0;
        for (int i = 0; i < NN / 1024; ++i) { boff[i] = acc; acc += bsum[i]; }
        row_start[NN] = acc;   // == NE
    }
}

__global__ void scan_apply_kernel(const int* __restrict__ cnt, const int* __restrict__ boff,
                                  int* __restrict__ row_start, float* __restrict__ deg_inv) {
    __shared__ int sd[1024];
    int t = threadIdx.x;
    int i = blockIdx.x * 1024 + t;
    int c = cnt[i];
    sd[t] = c;
    __syncthreads();
    for (int off = 1; off < 1024; off <<= 1) {
        int add = (t >= off) ? sd[t - off] : 0;
        __syncthreads();
        sd[t] += add;
        __syncthreads();
    }
    row_start[i] = boff[blockIdx.x] + sd[t] - c;     // exclusive
    deg_inv[i]   = (c > 0) ? (1.0f / (float)c) : 0.0f;
}

__global__ void scatter_kernel(const int* __restrict__ src, const int* __restrict__ dst,
                               const int* __restrict__ row_start, int* __restrict__ cursor,
                               int* __restrict__ sorted_src) {
    int e = blockIdx.x * blockDim.x + threadIdx.x;
    if (e < NE) {
        int d = dst[e];
        int p = atomicAdd(&cursor[d], 1);
        sorted_src[row_start[d] + p] = src[e];
    }
}

// ---------- high-ILP gather: sum of hin rows over [beg,end) ----------
// Lane-parallel index load + shfl broadcast; 8 independent accumulators
// -> up to 8 outstanding 128B row loads per 32-lane group.

__device__ __forceinline__ float gather_sum(const float* __restrict__ hin,
                                            const int* __restrict__ ss,
                                            int beg, int end, int lane) {
    float a0=0.f,a1=0.f,a2=0.f,a3=0.f,a4=0.f,a5=0.f,a6=0.f,a7=0.f;
    int cnt = end - beg, base = 0;
    while (base < cnt) {
        int rem = cnt - base;
        int chunk = rem > 32 ? 32 : rem;
        int idx = (lane < chunk) ? ss[beg + base + lane] : 0;
        int k = 0;
        for (; k + 8 <= chunk; k += 8) {
            int s0=__shfl(idx,k,32),   s1=__shfl(idx,k+1,32),
                s2=__shfl(idx,k+2,32), s3=__shfl(idx,k+3,32),
                s4=__shfl(idx,k+4,32), s5=__shfl(idx,k+5,32),
                s6=__shfl(idx,k+6,32), s7=__shfl(idx,k+7,32);
            a0 += hin[(s0<<5)+lane]; a1 += hin[(s1<<5)+lane];
            a2 += hin[(s2<<5)+lane]; a3 += hin[(s3<<5)+lane];
            a4 += hin[(s4<<5)+lane]; a5 += hin[(s5<<5)+lane];
            a6 += hin[(s6<<5)+lane]; a7 += hin[(s7<<5)+lane];
        }
        for (; k + 4 <= chunk; k += 4) {
            int s0=__shfl(idx,k,32),   s1=__shfl(idx,k+1,32),
                s2=__shfl(idx,k+2,32), s3=__shfl(idx,k+3,32);
            a0 += hin[(s0<<5)+lane]; a1 += hin[(s1<<5)+lane];
            a2 += hin[(s2<<5)+lane]; a3 += hin[(s3<<5)+lane];
        }
        for (; k < chunk; ++k) {
            int s0 = __shfl(idx,k,32);
            a0 += hin[(s0<<5)+lane];
        }
        base += chunk;
    }
    return ((a0+a1)+(a2+a3))+((a4+a5)+(a6+a7));
}

// ---------- fused GIN layer: hout = relu((hin + mean_agg(hin)) @ W + b) ----------

__global__ __launch_bounds__(256) void layer_kernel(
        const float* __restrict__ hin, const float* __restrict__ W, const float* __restrict__ b,
        const int* __restrict__ row_start, const int* __restrict__ sorted_src,
        const float* __restrict__ deg_inv, float* __restrict__ hout) {
    __shared__ float Wl[1024];
    __shared__ float bl[32];
    int t = threadIdx.x;
    for (int i = t; i < 1024; i += 256) Wl[i] = W[i];
    if (t < 32) bl[t] = b[t];
    __syncthreads();

    int node = (blockIdx.x << 3) + (t >> 5);
    int lane = t & 31;
    int beg = row_start[node];
    int end = row_start[node + 1];
    float a = gather_sum(hin, sorted_src, beg, end, lane);
    float v = hin[(node << 5) + lane] + a * deg_inv[node];
    float acc = bl[lane];
    #pragma unroll
    for (int k = 0; k < 32; ++k) {
        acc = fmaf(__shfl(v, k, 32), Wl[(k << 5) + lane], acc);
    }
    hout[(node << 5) + lane] = fmaxf(acc, 0.f);
}

// ---------- fused final neg layer + scoring ----------

__global__ __launch_bounds__(256) void layer_score_kernel(
        const float* __restrict__ hin, const float* __restrict__ W, const float* __restrict__ b,
        const int* __restrict__ row_start, const int* __restrict__ sorted_src,
        const float* __restrict__ deg_inv, const float* __restrict__ svec,
        float* __restrict__ loss) {
    __shared__ float Wl[1024];
    __shared__ float bl[32];
    __shared__ float sl[32];
    __shared__ float part[8];
    int t = threadIdx.x;
    for (int i = t; i < 1024; i += 256) Wl[i] = W[i];
    if (t < 32) { bl[t] = b[t]; sl[t] = svec[t]; }
    __syncthreads();

    int node = (blockIdx.x << 3) + (t >> 5);
    int lane = t & 31;
    int beg = row_start[node];
    int end = row_start[node + 1];
    float a = gather_sum(hin, sorted_src, beg, end, lane);
    float v = hin[(node << 5) + lane] + a * deg_inv[node];
    float acc = bl[lane];
    #pragma unroll
    for (int k = 0; k < 32; ++k) {
        acc = fmaf(__shfl(v, k, 32), Wl[(k << 5) + lane], acc);
    }
    acc = fmaxf(acc, 0.f);
    float w = acc * sl[lane];
    #pragma unroll
    for (int off = 16; off > 0; off >>= 1) w += __shfl_xor(w, off, 32);
    if (lane == 0) part[t >> 5] = softplus(w);   // target=0 -> softplus(+x)
    __syncthreads();
    if (t == 0) {
        float sum = 0.f;
        #pragma unroll
        for (int i = 0; i < 8; ++i) sum += part[i];
        atomicAdd(loss, sum);
    }
}

// ---------- readout ----------

__global__ __launch_bounds__(256) void colsum_kernel(const float* __restrict__ h,
                                                     float* __restrict__ colsum) {
    __shared__ float sd[256];
    int t = threadIdx.x;
    int stride = gridDim.x * 256;
    float acc = 0.f;
    for (int i = blockIdx.x * 256 + t; i < NN * HD; i += stride) acc += h[i];
    sd[t] = acc;
    __syncthreads();
    for (int off = 128; off >= 32; off >>= 1) {
        if (t < off) sd[t] += sd[t + off];
        __syncthreads();
    }
    if (t < 32) atomicAdd(&colsum[t], sd[t]);
}

__global__ void finalize_s_kernel(const float* __restrict__ colsum, const float* __restrict__ Wd,
                                  float* __restrict__ svec) {
    __shared__ float sm[32];
    int t = threadIdx.x;
    if (t < 32) {
        float m = colsum[t] / (float)NN;
        sm[t] = 1.f / (1.f + expf(-m));
    }
    __syncthreads();
    if (t < 32) {
        float acc = 0.f;
        for (int j = 0; j < 32; ++j) acc += Wd[t * 32 + j] * sm[j];
        svec[t] = acc;
    }
}

__global__ __launch_bounds__(256) void score_pos_kernel(const float* __restrict__ h,
                                                        const float* __restrict__ svec,
                                                        float* __restrict__ loss) {
    __shared__ float sl[32];
    __shared__ float sd[256];
    int t = threadIdx.x;
    if (t < 32) sl[t] = svec[t];
    __syncthreads();
    float acc = 0.f;
    int stride = gridDim.x * 256;
    for (int n = blockIdx.x * 256 + t; n < NN; n += stride) {
        const float4* row = (const float4*)(h + (n << 5));
        float dot = 0.f;
        #pragma unroll
        for (int q = 0; q < 8; ++q) {
            float4 r = row[q];
            dot += r.x * sl[q * 4 + 0] + r.y * sl[q * 4 + 1]
                 + r.z * sl[q * 4 + 2] + r.w * sl[q * 4 + 3];
        }
        acc += softplus(-dot);   // target=1 -> softplus(-x)
    }
    sd[t] = acc;
    __syncthreads();
    for (int off = 128; off > 0; off >>= 1) {
        if (t < off) sd[t] += sd[t + off];
        __syncthreads();
    }
    if (t == 0) atomicAdd(loss, sd[0]);
}

__global__ void perm_gather_kernel(const float* __restrict__ feat, const int* __restrict__ perm,
                                   float* __restrict__ out) {
    int i = blockIdx.x * blockDim.x + threadIdx.x;   // over NN*8 float4s
    int n = i >> 3, q = i & 7;
    ((float4*)out)[i] = ((const float4*)(feat + ((size_t)perm[n] << 5)))[q];
}

__global__ void final_kernel(const float* __restrict__ loss, float* __restrict__ out) {
    if (threadIdx.x == 0 && blockIdx.x == 0)
        out[0] = (loss[0] + loss[1]) / (float)NN;
}

// ---------- launch ----------

extern "C" void kernel_launch(void* const* d_in, const int* in_sizes, int n_in,
                              void* d_out, int out_size, void* d_ws, size_t ws_size,
                              hipStream_t stream) {
    const float* feature = (const float*)d_in[0];
    const float* W1 = (const float*)d_in[1];
    const float* b1 = (const float*)d_in[2];
    const float* W2 = (const float*)d_in[3];
    const float* b2 = (const float*)d_in[4];
    const float* Wd = (const float*)d_in[5];
    const int* src  = (const int*)d_in[6];
    const int* dst  = (const int*)d_in[7];
    const int* perm = (const int*)d_in[8];
    // d_in[9] = cluster_idx: irrelevant (equal-size disjoint clusters -> global mean)
    float* out = (float*)d_out;

    char* ws = (char*)d_ws;
    size_t off = 0;
    auto alloc = [&](size_t bytes) -> char* {
        char* p = ws + off;
        off += (bytes + 255) & ~(size_t)255;
        return p;
    };
    int*   cursor     = (int*)  alloc((size_t)NN * 4);
    int*   row_start  = (int*)  alloc((size_t)(NN + 1) * 4);
    int*   bsum       = (int*)  alloc(128 * 4);
    int*   boff       = (int*)  alloc(128 * 4);
    int*   sorted_src = (int*)  alloc((size_t)NE * 4);
    float* deg_inv    = (float*)alloc((size_t)NN * 4);
    float* hA         = (float*)alloc((size_t)NN * HD * 4);
    float* hB         = (float*)alloc((size_t)NN * HD * 4);
    float* colsum     = (float*)alloc(32 * 4);
    float* svec       = (float*)alloc(32 * 4);
    float* loss       = (float*)alloc(2 * 4);

    hipMemsetAsync(cursor, 0, (size_t)NN * 4, stream);
    hipMemsetAsync(colsum, 0, 32 * 4, stream);
    hipMemsetAsync(loss, 0, 2 * 4, stream);

    // CSR build (group edges by dst)
    hist_kernel<<<NE / 256, 256, 0, stream>>>(dst, cursor);
    block_sum_kernel<<<NN / 1024, 1024, 0, stream>>>(cursor, bsum);
    scan_bsum_kernel<<<1, 64, 0, stream>>>(bsum, boff, row_start);
    scan_apply_kernel<<<NN / 1024, 1024, 0, stream>>>(cursor, boff, row_start, deg_inv);
    hipMemsetAsync(cursor, 0, (size_t)NN * 4, stream);
    scatter_kernel<<<NE / 256, 256, 0, stream>>>(src, dst, row_start, cursor, sorted_src);

    // positive pass
    layer_kernel<<<NN / 8, 256, 0, stream>>>(feature, W1, b1, row_start, sorted_src, deg_inv, hA);
    layer_kernel<<<NN / 8, 256, 0, stream>>>(hA, W2, b2, row_start, sorted_src, deg_inv, hB);

    // readout: s = Wd @ sigmoid(mean(pos))
    colsum_kernel<<<2048, 256, 0, stream>>>(hB, colsum);
    finalize_s_kernel<<<1, 64, 0, stream>>>(colsum, Wd, svec);

    // positive scores
    score_pos_kernel<<<2048, 256, 0, stream>>>(hB, svec, loss);

    // negative pass (corrupted features), second layer fused with scoring
    perm_gather_kernel<<<(NN * 8) / 256, 256, 0, stream>>>(feature, perm, hA);
    layer_kernel<<<NN / 8, 256, 0, stream>>>(hA, W1, b1, row_start, sorted_src, deg_inv, hB);
    layer_score_kernel<<<NN / 8, 256, 0, stream>>>(hB, W2, b2, row_start, sorted_src, deg_inv,
                                                   svec, loss + 1);

    final_kernel<<<1, 64, 0, stream>>>(loss, out);
}

// Round 3
// 483.409 us; speedup vs baseline: 1.8770x; 1.4818x over previous
//
#include <hip/hip_runtime.h>
#include <math.h>

#define NN 131072      // nodes
#define NE 2097152     // edges
#define HD 32          // feature dim

__device__ __forceinline__ float softplus(float x) {
    return fmaxf(x, 0.f) + log1pf(expf(-fabsf(x)));
}
__device__ __forceinline__ float bf2f(unsigned short u) {
    return __uint_as_float(((unsigned int)u) << 16);
}
__device__ __forceinline__ unsigned short f2bf(float f) {   // round-to-nearest-even
    unsigned int u = __float_as_uint(f);
    return (unsigned short)((u + 0x7FFFu + ((u >> 16) & 1u)) >> 16);
}

// ---------- CSR build ----------

__global__ void hist_kernel(const int* __restrict__ dst, int* __restrict__ cnt) {
    int e = blockIdx.x * blockDim.x + threadIdx.x;
    if (e < NE) atomicAdd(&cnt[dst[e]], 1);
}

__global__ void block_sum_kernel(const int* __restrict__ cnt, int* __restrict__ bsum) {
    __shared__ int sd[1024];
    int t = threadIdx.x;
    sd[t] = cnt[blockIdx.x * 1024 + t];
    __syncthreads();
    for (int off = 512; off > 0; off >>= 1) {
        if (t < off) sd[t] += sd[t + off];
        __syncthreads();
    }
    if (t == 0) bsum[blockIdx.x] = sd[0];
}

__global__ void scan_bsum_kernel(const int* __restrict__ bsum, int* __restrict__ boff,
                                 int* __restrict__ row_start) {
    if (threadIdx.x == 0 && blockIdx.x == 0) {
        int acc = 0;
        for (int i = 0; i < NN / 1024; ++i) { boff[i] = acc; acc += bsum[i]; }
        row_start[NN] = acc;   // == NE
    }
}

__global__ void scan_apply_kernel(const int* __restrict__ cnt, const int* __restrict__ boff,
                                  int* __restrict__ row_start, float* __restrict__ deg_inv) {
    __shared__ int sd[1024];
    int t = threadIdx.x;
    int i = blockIdx.x * 1024 + t;
    int c = cnt[i];
    sd[t] = c;
    __syncthreads();
    for (int off = 1; off < 1024; off <<= 1) {
        int add = (t >= off) ? sd[t - off] : 0;
        __syncthreads();
        sd[t] += add;
        __syncthreads();
    }
    row_start[i] = boff[blockIdx.x] + sd[t] - c;     // exclusive
    deg_inv[i]   = (c > 0) ? (1.0f / (float)c) : 0.0f;
}

__global__ void scatter_kernel(const int* __restrict__ src, const int* __restrict__ dst,
                               const int* __restrict__ row_start, int* __restrict__ cursor,
                               int* __restrict__ sorted_src) {
    int e = blockIdx.x * blockDim.x + threadIdx.x;
    if (e < NE) {
        int d = dst[e];
        int p = atomicAdd(&cursor[d], 1);
        sorted_src[row_start[d] + p] = src[e];
    }
}

// ---------- f32 -> bf16 table ----------

__global__ void to_bf16_kernel(const float* __restrict__ in, unsigned short* __restrict__ out) {
    int i = blockIdx.x * blockDim.x + threadIdx.x;   // over NN*HD/4
    float4 v = ((const float4*)in)[i];
    ushort4 o;
    o.x = f2bf(v.x); o.y = f2bf(v.y); o.z = f2bf(v.z); o.w = f2bf(v.w);
    ((ushort4*)out)[i] = o;
}

// ---------- fused dual GIN layer (pos + neg share indices/weights) ----------
// pos: out = relu((tabP[node] + mean_{s} tabP[s]) @ W + b)
// neg: out = relu((tabN[mapN(node)] + mean_{s} tabN[mapN(s)]) @ W + b), mapN=identity if null

__global__ __launch_bounds__(256) void layer_both_kernel(
        const unsigned short* __restrict__ tabP, const unsigned short* __restrict__ tabN,
        const int* __restrict__ mapN,
        const float* __restrict__ W, const float* __restrict__ b,
        const int* __restrict__ row_start, const int* __restrict__ sorted_src,
        const float* __restrict__ deg_inv,
        unsigned short* __restrict__ outP, unsigned short* __restrict__ outN) {
    __shared__ float Wl[1024];
    __shared__ float bl[32];
    int t = threadIdx.x;
    for (int i = t; i < 1024; i += 256) Wl[i] = W[i];
    if (t < 32) bl[t] = b[t];
    __syncthreads();

    int node = (blockIdx.x << 3) + (t >> 5);
    int lane = t & 31;
    int beg = row_start[node];
    int end = row_start[node + 1];
    int selfN = mapN ? mapN[node] : node;
    float sP = bf2f(tabP[(node << 5) + lane]);
    float sN = bf2f(tabN[(selfN << 5) + lane]);

    float p0 = 0.f, p1 = 0.f, p2 = 0.f, p3 = 0.f;
    float n0 = 0.f, n1 = 0.f, n2 = 0.f, n3 = 0.f;
    int cnt = end - beg, base = 0;
    while (base < cnt) {
        int rem = cnt - base;
        int chunk = rem > 32 ? 32 : rem;
        int sp = 0, sn = 0;
        if (lane < chunk) {
            sp = sorted_src[beg + base + lane];
            sn = mapN ? mapN[sp] : sp;
        }
        int k = 0;
        for (; k + 4 <= chunk; k += 4) {
            int i0 = __shfl(sp, k, 32),     i1 = __shfl(sp, k + 1, 32),
                i2 = __shfl(sp, k + 2, 32), i3 = __shfl(sp, k + 3, 32);
            int j0 = __shfl(sn, k, 32),     j1 = __shfl(sn, k + 1, 32),
                j2 = __shfl(sn, k + 2, 32), j3 = __shfl(sn, k + 3, 32);
            p0 += bf2f(tabP[(i0 << 5) + lane]); p1 += bf2f(tabP[(i1 << 5) + lane]);
            p2 += bf2f(tabP[(i2 << 5) + lane]); p3 += bf2f(tabP[(i3 << 5) + lane]);
            n0 += bf2f(tabN[(j0 << 5) + lane]); n1 += bf2f(tabN[(j1 << 5) + lane]);
            n2 += bf2f(tabN[(j2 << 5) + lane]); n3 += bf2f(tabN[(j3 << 5) + lane]);
        }
        for (; k < chunk; ++k) {
            int i0 = __shfl(sp, k, 32), j0 = __shfl(sn, k, 32);
            p0 += bf2f(tabP[(i0 << 5) + lane]);
            n0 += bf2f(tabN[(j0 << 5) + lane]);
        }
        base += chunk;
    }
    float di = deg_inv[node];
    float vP = sP + ((p0 + p1) + (p2 + p3)) * di;
    float vN = sN + ((n0 + n1) + (n2 + n3)) * di;
    float aP = bl[lane], aN = bl[lane];
    #pragma unroll
    for (int k = 0; k < 32; ++k) {
        float wk = Wl[(k << 5) + lane];
        aP = fmaf(__shfl(vP, k, 32), wk, aP);
        aN = fmaf(__shfl(vN, k, 32), wk, aN);
    }
    outP[(node << 5) + lane] = f2bf(fmaxf(aP, 0.f));
    outN[(node << 5) + lane] = f2bf(fmaxf(aN, 0.f));
}

// ---------- readout ----------

__global__ __launch_bounds__(256) void colsum_kernel(const unsigned short* __restrict__ h,
                                                     float* __restrict__ colsum) {
    __shared__ float sd[256];
    int t = threadIdx.x;
    int stride = gridDim.x * 256;   // multiple of 32 -> column (t&31) fixed per thread
    float acc = 0.f;
    for (int i = blockIdx.x * 256 + t; i < NN * HD; i += stride) acc += bf2f(h[i]);
    sd[t] = acc;
    __syncthreads();
    for (int off = 128; off >= 32; off >>= 1) {
        if (t < off) sd[t] += sd[t + off];
        __syncthreads();
    }
    if (t < 32) atomicAdd(&colsum[t], sd[t]);
}

__global__ void finalize_s_kernel(const float* __restrict__ colsum, const float* __restrict__ Wd,
                                  float* __restrict__ svec) {
    __shared__ float sm[32];
    int t = threadIdx.x;
    if (t < 32) {
        float m = colsum[t] / (float)NN;
        sm[t] = 1.f / (1.f + expf(-m));
    }
    __syncthreads();
    if (t < 32) {
        float acc = 0.f;
        for (int j = 0; j < 32; ++j) acc += Wd[t * 32 + j] * sm[j];
        svec[t] = acc;
    }
}

__global__ __launch_bounds__(256) void score_both_kernel(const unsigned short* __restrict__ hP,
                                                         const unsigned short* __restrict__ hN,
                                                         const float* __restrict__ svec,
                                                         float* __restrict__ loss) {
    __shared__ float sl[32];
    __shared__ float sdP[256];
    __shared__ float sdN[256];
    int t = threadIdx.x;
    if (t < 32) sl[t] = svec[t];
    __syncthreads();
    float accP = 0.f, accN = 0.f;
    int stride = gridDim.x * 256;
    for (int n = blockIdx.x * 256 + t; n < NN; n += stride) {
        const ushort4* rp = (const ushort4*)(hP + (n << 5));
        const ushort4* rn = (const ushort4*)(hN + (n << 5));
        float dp = 0.f, dn = 0.f;
        #pragma unroll
        for (int q = 0; q < 8; ++q) {
            ushort4 a = rp[q], c = rn[q];
            dp += bf2f(a.x) * sl[4*q] + bf2f(a.y) * sl[4*q+1]
                + bf2f(a.z) * sl[4*q+2] + bf2f(a.w) * sl[4*q+3];
            dn += bf2f(c.x) * sl[4*q] + bf2f(c.y) * sl[4*q+1]
                + bf2f(c.z) * sl[4*q+2] + bf2f(c.w) * sl[4*q+3];
        }
        accP += softplus(-dp);   // target=1
        accN += softplus(dn);    // target=0
    }
    sdP[t] = accP; sdN[t] = accN;
    __syncthreads();
    for (int off = 128; off > 0; off >>= 1) {
        if (t < off) { sdP[t] += sdP[t + off]; sdN[t] += sdN[t + off]; }
        __syncthreads();
    }
    if (t == 0) { atomicAdd(&loss[0], sdP[0]); atomicAdd(&loss[1], sdN[0]); }
}

__global__ void final_kernel(const float* __restrict__ loss, float* __restrict__ out) {
    if (threadIdx.x == 0 && blockIdx.x == 0)
        out[0] = (loss[0] + loss[1]) / (float)NN;
}

// ---------- launch ----------

extern "C" void kernel_launch(void* const* d_in, const int* in_sizes, int n_in,
                              void* d_out, int out_size, void* d_ws, size_t ws_size,
                              hipStream_t stream) {
    const float* feature = (const float*)d_in[0];
    const float* W1 = (const float*)d_in[1];
    const float* b1 = (const float*)d_in[2];
    const float* W2 = (const float*)d_in[3];
    const float* b2 = (const float*)d_in[4];
    const float* Wd = (const float*)d_in[5];
    const int* src  = (const int*)d_in[6];
    const int* dst  = (const int*)d_in[7];
    const int* perm = (const int*)d_in[8];
    // d_in[9] = cluster_idx: irrelevant (equal-size disjoint clusters -> global mean)
    float* out = (float*)d_out;

    char* ws = (char*)d_ws;
    size_t off = 0;
    auto alloc = [&](size_t bytes) -> char* {
        char* p = ws + off;
        off += (bytes + 255) & ~(size_t)255;
        return p;
    };
    int*   cursor     = (int*)  alloc((size_t)NN * 4);
    int*   row_start  = (int*)  alloc((size_t)(NN + 1) * 4);
    int*   bsum       = (int*)  alloc(128 * 4);
    int*   boff       = (int*)  alloc(128 * 4);
    int*   sorted_src = (int*)  alloc((size_t)NE * 4);
    float* deg_inv    = (float*)alloc((size_t)NN * 4);
    unsigned short* featb = (unsigned short*)alloc((size_t)NN * HD * 2);  // reused as hB
    unsigned short* hA    = (unsigned short*)alloc((size_t)NN * HD * 2);
    unsigned short* hC    = (unsigned short*)alloc((size_t)NN * HD * 2);
    unsigned short* hD    = (unsigned short*)alloc((size_t)NN * HD * 2);
    float* colsum     = (float*)alloc(32 * 4);
    float* svec       = (float*)alloc(32 * 4);
    float* loss       = (float*)alloc(2 * 4);
    unsigned short* hB = featb;   // layer2 does not read featb

    hipMemsetAsync(cursor, 0, (size_t)NN * 4, stream);
    hipMemsetAsync(colsum, 0, 32 * 4, stream);
    hipMemsetAsync(loss, 0, 2 * 4, stream);

    // CSR build (group edges by dst)
    hist_kernel<<<NE / 256, 256, 0, stream>>>(dst, cursor);
    block_sum_kernel<<<NN / 1024, 1024, 0, stream>>>(cursor, bsum);
    scan_bsum_kernel<<<1, 64, 0, stream>>>(bsum, boff, row_start);
    scan_apply_kernel<<<NN / 1024, 1024, 0, stream>>>(cursor, boff, row_start, deg_inv);
    hipMemsetAsync(cursor, 0, (size_t)NN * 4, stream);
    scatter_kernel<<<NE / 256, 256, 0, stream>>>(src, dst, row_start, cursor, sorted_src);

    // feature -> bf16 table
    to_bf16_kernel<<<(NN * HD / 4) / 256, 256, 0, stream>>>(feature, featb);

    // layer 1 (pos + neg fused; neg composes perm on the fly)
    layer_both_kernel<<<NN / 8, 256, 0, stream>>>(featb, featb, perm, W1, b1,
                                                  row_start, sorted_src, deg_inv, hA, hC);
    // layer 2 (pos + neg fused)
    layer_both_kernel<<<NN / 8, 256, 0, stream>>>(hA, hC, nullptr, W2, b2,
                                                  row_start, sorted_src, deg_inv, hB, hD);

    // readout: s = Wd @ sigmoid(mean(pos))
    colsum_kernel<<<1024, 256, 0, stream>>>(hB, colsum);
    finalize_s_kernel<<<1, 64, 0, stream>>>(colsum, Wd, svec);

    // scores (pos + neg streaming)
    score_both_kernel<<<1024, 256, 0, stream>>>(hB, hD, svec, loss);

    final_kernel<<<1, 64, 0, stream>>>(loss, out);
}

// Round 4
// 326.025 us; speedup vs baseline: 2.7831x; 1.4827x over previous
//
#include <hip/hip_runtime.h>
#include <math.h>

#define NN 131072      // nodes
#define NE 2097152     // edges
#define HD 32          // feature dim
#define NBUCK 256      // buckets of 512 nodes
#define BSH 9          // node >> 9 -> bucket
#define BNODES 512     // nodes per bucket
#define CHUNK 8192     // edges per binning block (NE/256)
#define MAXB 10240     // LDS stage capacity per bucket (max bucket ~8.5K)

__device__ __forceinline__ float softplus(float x) {
    return fmaxf(x, 0.f) + log1pf(expf(-fabsf(x)));
}
__device__ __forceinline__ float bf2f(unsigned short u) {
    return __uint_as_float(((unsigned int)u) << 16);
}
__device__ __forceinline__ unsigned short f2bf(float f) {   // round-to-nearest-even
    unsigned int u = __float_as_uint(f);
    return (unsigned short)((u + 0x7FFFu + ((u >> 16) & 1u)) >> 16);
}

// ---------- CSR build: block-private LDS counting sort (no global atomics) ----------

// Each block bins its private 8192-edge chunk by bucket, exact LDS placement,
// coalesced write to records[block*CHUNK ...]. Records: (local_dst<<17)|src.
__global__ __launch_bounds__(256) void bin_kernel(
        const int* __restrict__ src, const int* __restrict__ dst,
        unsigned int* __restrict__ records,
        int* __restrict__ cnt_tab, int* __restrict__ off_tab) {
    __shared__ unsigned int stage[CHUNK];
    __shared__ int cntA[NBUCK], offA[NBUCK], wcur[NBUCK];
    int t = threadIdx.x, j = blockIdx.x;
    int base = j * CHUNK;
    cntA[t] = 0;
    __syncthreads();
    #pragma unroll 4
    for (int i = 0; i < CHUNK / 256; ++i) {
        int d = dst[base + t + i * 256];
        atomicAdd(&cntA[d >> BSH], 1);
    }
    __syncthreads();
    // inclusive scan of cntA -> offA
    offA[t] = cntA[t];
    __syncthreads();
    for (int off = 1; off < NBUCK; off <<= 1) {
        int y = (t >= off) ? offA[t - off] : 0;
        __syncthreads();
        offA[t] += y;
        __syncthreads();
    }
    int excl = offA[t] - cntA[t];
    wcur[t] = excl;
    __syncthreads();
    #pragma unroll 4
    for (int i = 0; i < CHUNK / 256; ++i) {
        int e = base + t + i * 256;
        int d = dst[e], s = src[e];
        int slot = atomicAdd(&wcur[d >> BSH], 1);
        stage[slot] = ((unsigned int)(d & (BNODES - 1)) << 17) | (unsigned int)s;
    }
    __syncthreads();
    #pragma unroll 4
    for (int i = 0; i < CHUNK / 256; ++i)
        records[base + t + i * 256] = stage[t + i * 256];
    cnt_tab[j * NBUCK + t] = cntA[t];
    off_tab[j * NBUCK + t] = excl;
}

// Column-sum the per-(block,bucket) counts -> global bucket bases.
__global__ void bucket_scan_kernel(const int* __restrict__ cnt_tab,
                                   int* __restrict__ bucket_base,
                                   int* __restrict__ row_start) {
    __shared__ int tot[NBUCK];
    int t = threadIdx.x;
    int s = 0;
    for (int j = 0; j < 256; ++j) s += cnt_tab[j * NBUCK + t];
    tot[t] = s;
    __syncthreads();
    for (int off = 1; off < NBUCK; off <<= 1) {
        int y = (t >= off) ? tot[t - off] : 0;
        __syncthreads();
        tot[t] += y;
        __syncthreads();
    }
    bucket_base[t] = tot[t] - s;   // exclusive
    if (t == NBUCK - 1) {
        bucket_base[NBUCK] = tot[t];   // == NE
        row_start[NN] = tot[t];
    }
}

// One block per bucket: per-node count -> scan -> row_start/deg_inv,
// then exact placement of srcs in LDS, coalesced write of sorted_src.
__global__ __launch_bounds__(512) void csr_sort_kernel(
        const unsigned int* __restrict__ records,
        const int* __restrict__ cnt_tab, const int* __restrict__ off_tab,
        const int* __restrict__ bucket_base,
        int* __restrict__ sorted_src, int* __restrict__ row_start,
        float* __restrict__ deg_inv) {
    __shared__ int stageS[MAXB];
    __shared__ int cnt[BNODES], rs[BNODES], wcur[BNODES];
    int t = threadIdx.x, b = blockIdx.x;
    int wave = t >> 6, lane = t & 63;   // 8 waves
    cnt[t] = 0;
    __syncthreads();
    for (int j = wave; j < 256; j += 8) {
        int c = cnt_tab[j * NBUCK + b];
        int sbase = j * CHUNK + off_tab[j * NBUCK + b];
        for (int k = lane; k < c; k += 64)
            atomicAdd(&cnt[records[sbase + k] >> 17], 1);
    }
    __syncthreads();
    rs[t] = cnt[t];
    __syncthreads();
    for (int off = 1; off < BNODES; off <<= 1) {
        int y = (t >= off) ? rs[t - off] : 0;
        __syncthreads();
        rs[t] += y;
        __syncthreads();
    }
    int excl = rs[t] - cnt[t];
    wcur[t] = excl;
    int gb = bucket_base[b];
    row_start[b * BNODES + t] = gb + excl;
    deg_inv[b * BNODES + t] = cnt[t] ? (1.0f / (float)cnt[t]) : 0.0f;
    __syncthreads();
    for (int j = wave; j < 256; j += 8) {
        int c = cnt_tab[j * NBUCK + b];
        int sbase = j * CHUNK + off_tab[j * NBUCK + b];
        for (int k = lane; k < c; k += 64) {
            unsigned int r = records[sbase + k];
            int slot = atomicAdd(&wcur[r >> 17], 1);
            stageS[slot] = (int)(r & 0x1FFFFu);
        }
    }
    __syncthreads();
    int btot = bucket_base[b + 1] - gb;
    for (int k = t; k < btot; k += 512) sorted_src[gb + k] = stageS[k];
}

// ---------- f32 -> bf16 table ----------

__global__ void to_bf16_kernel(const float* __restrict__ in, unsigned short* __restrict__ out) {
    int i = blockIdx.x * blockDim.x + threadIdx.x;   // over NN*HD/4
    float4 v = ((const float4*)in)[i];
    ushort4 o;
    o.x = f2bf(v.x); o.y = f2bf(v.y); o.z = f2bf(v.z); o.w = f2bf(v.w);
    ((ushort4*)out)[i] = o;
}

// ---------- fused dual GIN layer (pos + neg share indices/weights) ----------

__global__ __launch_bounds__(256) void layer_both_kernel(
        const unsigned short* __restrict__ tabP, const unsigned short* __restrict__ tabN,
        const int* __restrict__ mapN,
        const float* __restrict__ W, const float* __restrict__ b,
        const int* __restrict__ row_start, const int* __restrict__ sorted_src,
        const float* __restrict__ deg_inv,
        unsigned short* __restrict__ outP, unsigned short* __restrict__ outN) {
    __shared__ float Wl[1024];
    __shared__ float bl[32];
    int t = threadIdx.x;
    for (int i = t; i < 1024; i += 256) Wl[i] = W[i];
    if (t < 32) bl[t] = b[t];
    __syncthreads();

    int node = (blockIdx.x << 3) + (t >> 5);
    int lane = t & 31;
    int beg = row_start[node];
    int end = row_start[node + 1];
    int selfN = mapN ? mapN[node] : node;
    float sP = bf2f(tabP[(node << 5) + lane]);
    float sN = bf2f(tabN[(selfN << 5) + lane]);

    float p0 = 0.f, p1 = 0.f, p2 = 0.f, p3 = 0.f;
    float n0 = 0.f, n1 = 0.f, n2 = 0.f, n3 = 0.f;
    int cnt = end - beg, base = 0;
    while (base < cnt) {
        int rem = cnt - base;
        int chunk = rem > 32 ? 32 : rem;
        int sp = 0, sn = 0;
        if (lane < chunk) {
            sp = sorted_src[beg + base + lane];
            sn = mapN ? mapN[sp] : sp;
        }
        int k = 0;
        for (; k + 4 <= chunk; k += 4) {
            int i0 = __shfl(sp, k, 32),     i1 = __shfl(sp, k + 1, 32),
                i2 = __shfl(sp, k + 2, 32), i3 = __shfl(sp, k + 3, 32);
            int j0 = __shfl(sn, k, 32),     j1 = __shfl(sn, k + 1, 32),
                j2 = __shfl(sn, k + 2, 32), j3 = __shfl(sn, k + 3, 32);
            p0 += bf2f(tabP[(i0 << 5) + lane]); p1 += bf2f(tabP[(i1 << 5) + lane]);
            p2 += bf2f(tabP[(i2 << 5) + lane]); p3 += bf2f(tabP[(i3 << 5) + lane]);
            n0 += bf2f(tabN[(j0 << 5) + lane]); n1 += bf2f(tabN[(j1 << 5) + lane]);
            n2 += bf2f(tabN[(j2 << 5) + lane]); n3 += bf2f(tabN[(j3 << 5) + lane]);
        }
        for (; k < chunk; ++k) {
            int i0 = __shfl(sp, k, 32), j0 = __shfl(sn, k, 32);
            p0 += bf2f(tabP[(i0 << 5) + lane]);
            n0 += bf2f(tabN[(j0 << 5) + lane]);
        }
        base += chunk;
    }
    float di = deg_inv[node];
    float vP = sP + ((p0 + p1) + (p2 + p3)) * di;
    float vN = sN + ((n0 + n1) + (n2 + n3)) * di;
    float aP = bl[lane], aN = bl[lane];
    #pragma unroll
    for (int k = 0; k < 32; ++k) {
        float wk = Wl[(k << 5) + lane];
        aP = fmaf(__shfl(vP, k, 32), wk, aP);
        aN = fmaf(__shfl(vN, k, 32), wk, aN);
    }
    outP[(node << 5) + lane] = f2bf(fmaxf(aP, 0.f));
    outN[(node << 5) + lane] = f2bf(fmaxf(aN, 0.f));
}

// ---------- readout ----------

__global__ __launch_bounds__(256) void colsum_kernel(const unsigned short* __restrict__ h,
                                                     float* __restrict__ colsum) {
    __shared__ float sd[256];
    int t = threadIdx.x;
    int stride = gridDim.x * 256;   // multiple of 32 -> column (t&31) fixed per thread
    float acc = 0.f;
    for (int i = blockIdx.x * 256 + t; i < NN * HD; i += stride) acc += bf2f(h[i]);
    sd[t] = acc;
    __syncthreads();
    for (int off = 128; off >= 32; off >>= 1) {
        if (t < off) sd[t] += sd[t + off];
        __syncthreads();
    }
    if (t < 32) atomicAdd(&colsum[t], sd[t]);
}

__global__ void finalize_s_kernel(const float* __restrict__ colsum, const float* __restrict__ Wd,
                                  float* __restrict__ svec) {
    __shared__ float sm[32];
    int t = threadIdx.x;
    if (t < 32) {
        float m = colsum[t] / (float)NN;
        sm[t] = 1.f / (1.f + expf(-m));
    }
    __syncthreads();
    if (t < 32) {
        float acc = 0.f;
        for (int j = 0; j < 32; ++j) acc += Wd[t * 32 + j] * sm[j];
        svec[t] = acc;
    }
}

__global__ __launch_bounds__(256) void score_both_kernel(const unsigned short* __restrict__ hP,
                                                         const unsigned short* __restrict__ hN,
                                                         const float* __restrict__ svec,
                                                         float* __restrict__ loss) {
    __shared__ float sl[32];
    __shared__ float sdP[256];
    __shared__ float sdN[256];
    int t = threadIdx.x;
    if (t < 32) sl[t] = svec[t];
    __syncthreads();
    float accP = 0.f, accN = 0.f;
    int stride = gridDim.x * 256;
    for (int n = blockIdx.x * 256 + t; n < NN; n += stride) {
        const ushort4* rp = (const ushort4*)(hP + (n << 5));
        const ushort4* rn = (const ushort4*)(hN + (n << 5));
        float dp = 0.f, dn = 0.f;
        #pragma unroll
        for (int q = 0; q < 8; ++q) {
            ushort4 a = rp[q], c = rn[q];
            dp += bf2f(a.x) * sl[4*q] + bf2f(a.y) * sl[4*q+1]
                + bf2f(a.z) * sl[4*q+2] + bf2f(a.w) * sl[4*q+3];
            dn += bf2f(c.x) * sl[4*q] + bf2f(c.y) * sl[4*q+1]
                + bf2f(c.z) * sl[4*q+2] + bf2f(c.w) * sl[4*q+3];
        }
        accP += softplus(-dp);   // target=1
        accN += softplus(dn);    // target=0
    }
    sdP[t] = accP; sdN[t] = accN;
    __syncthreads();
    for (int off = 128; off > 0; off >>= 1) {
        if (t < off) { sdP[t] += sdP[t + off]; sdN[t] += sdN[t + off]; }
        __syncthreads();
    }
    if (t == 0) { atomicAdd(&loss[0], sdP[0]); atomicAdd(&loss[1], sdN[0]); }
}

__global__ void final_kernel(const float* __restrict__ loss, float* __restrict__ out) {
    if (threadIdx.x == 0 && blockIdx.x == 0)
        out[0] = (loss[0] + loss[1]) / (float)NN;
}

// ---------- launch ----------

extern "C" void kernel_launch(void* const* d_in, const int* in_sizes, int n_in,
                              void* d_out, int out_size, void* d_ws, size_t ws_size,
                              hipStream_t stream) {
    const float* feature = (const float*)d_in[0];
    const float* W1 = (const float*)d_in[1];
    const float* b1 = (const float*)d_in[2];
    const float* W2 = (const float*)d_in[3];
    const float* b2 = (const float*)d_in[4];
    const float* Wd = (const float*)d_in[5];
    const int* src  = (const int*)d_in[6];
    const int* dst  = (const int*)d_in[7];
    const int* perm = (const int*)d_in[8];
    // d_in[9] = cluster_idx: irrelevant (equal-size disjoint clusters -> global mean)
    float* out = (float*)d_out;

    char* ws = (char*)d_ws;
    size_t off = 0;
    auto alloc = [&](size_t bytes) -> char* {
        char* p = ws + off;
        off += (bytes + 255) & ~(size_t)255;
        return p;
    };
    int*   row_start  = (int*)  alloc((size_t)(NN + 1) * 4);
    int*   sorted_src = (int*)  alloc((size_t)NE * 4);
    int*   cnt_tab    = (int*)  alloc((size_t)256 * NBUCK * 4);
    int*   off_tab    = (int*)  alloc((size_t)256 * NBUCK * 4);
    int*   bucket_base= (int*)  alloc((size_t)(NBUCK + 1) * 4);
    float* deg_inv    = (float*)alloc((size_t)NN * 4);
    unsigned short* featb = (unsigned short*)alloc((size_t)NN * HD * 2);  // reused as hB
    unsigned short* hA    = (unsigned short*)alloc((size_t)NN * HD * 2);  // records alias
    unsigned short* hC    = (unsigned short*)alloc((size_t)NN * HD * 2);
    unsigned short* hD    = (unsigned short*)alloc((size_t)NN * HD * 2);
    float* colsum     = (float*)alloc(32 * 4);
    float* svec       = (float*)alloc(32 * 4);
    float* loss       = (float*)alloc(2 * 4);
    unsigned short* hB = featb;            // layer2 does not read featb
    unsigned int* records = (unsigned int*)hA;   // dead until layer1 writes hA

    hipMemsetAsync(colsum, 0, 32 * 4, stream);
    hipMemsetAsync(loss, 0, 2 * 4, stream);

    // CSR build: block-private counting sort, all writes coalesced
    bin_kernel<<<256, 256, 0, stream>>>(src, dst, records, cnt_tab, off_tab);
    bucket_scan_kernel<<<1, NBUCK, 0, stream>>>(cnt_tab, bucket_base, row_start);
    csr_sort_kernel<<<NBUCK, 512, 0, stream>>>(records, cnt_tab, off_tab, bucket_base,
                                               sorted_src, row_start, deg_inv);

    // feature -> bf16 table
    to_bf16_kernel<<<(NN * HD / 4) / 256, 256, 0, stream>>>(feature, featb);

    // layer 1 (pos + neg fused; neg composes perm on the fly)
    layer_both_kernel<<<NN / 8, 256, 0, stream>>>(featb, featb, perm, W1, b1,
                                                  row_start, sorted_src, deg_inv, hA, hC);
    // layer 2 (pos + neg fused)
    layer_both_kernel<<<NN / 8, 256, 0, stream>>>(hA, hC, nullptr, W2, b2,
                                                  row_start, sorted_src, deg_inv, hB, hD);

    // readout: s = Wd @ sigmoid(mean(pos))
    colsum_kernel<<<1024, 256, 0, stream>>>(hB, colsum);
    finalize_s_kernel<<<1, 64, 0, stream>>>(colsum, Wd, svec);

    // scores (pos + neg streaming)
    score_both_kernel<<<1024, 256, 0, stream>>>(hB, hD, svec, loss);

    final_kernel<<<1, 64, 0, stream>>>(loss, out);
}